// Round 5
// baseline (889.639 us; speedup 1.0000x reference)
//
#include <hip/hip_runtime.h>
#include <hip/hip_bf16.h>
#include <hip/hip_cooperative_groups.h>

namespace cg = cooperative_groups;

// RecursiveNet bf16-MFMA, round 5: ONE cooperative dispatch.
// Phases (grid.sync between): [bias+repack] [pair01] [pair23] [pair45]
// [pair67] [pair89] [tail 10..17 on block 0, global ping-pong + threadfence].
// Math identical to R4 (same bf16 rounding points) -> absmax must match.

typedef __bf16 v8bf __attribute__((ext_vector_type(8)));
typedef float v16f __attribute__((ext_vector_type(16)));

__device__ __forceinline__ ushort f2bf(float f) {
    __hip_bfloat16 h = __float2bfloat16(f);
    return *reinterpret_cast<ushort*>(&h);
}
__device__ __forceinline__ unsigned pack2(float lo, float hi) {
    return (unsigned)f2bf(lo) | ((unsigned)f2bf(hi) << 16);
}
__device__ __forceinline__ float leaky(float y) { return (y >= 0.f) ? y : 0.2f * y; }

#define ZACC {0.f,0.f,0.f,0.f,0.f,0.f,0.f,0.f,0.f,0.f,0.f,0.f,0.f,0.f,0.f,0.f}

__device__ __forceinline__ void load_af(const ushort* __restrict__ A, v8bf* af) {
    const int lane = threadIdx.x & 63;
    const int w = threadIdx.x >> 6;
    const ushort* Arow = A + (size_t)(w * 32 + (lane & 31)) * 256 + (lane >> 5) * 8;
#pragma unroll
    for (int s = 0; s < 16; ++s) af[s] = *(const v8bf*)&Arow[s * 16];
}

// ---------------------------------------------------------------------------
// Fused stage pair: one tile-group -> 32 outputs of the second stage.
// xin: 132 staged rows (swizzled), mid: 65 pooled rows (swizzled). 2 barriers.
__device__ void do_pair(int U, const ushort* __restrict__ Xin,
                        const float* __restrict__ x0, const int* __restrict__ perm,
                        const v8bf* af, const float* __restrict__ Bst2,
                        ushort* __restrict__ Y, int Lin, int Lp2, int stage0,
                        ushort* xin, ushort* mid) {
    const int tid = threadIdx.x;
    const int lane = tid & 63;
    const int w = tid >> 6;
    const int n31 = lane & 31;
    const int h = lane >> 5;
    const int t0 = U * 4;

    for (int idx = tid; idx < 132 * 16; idx += 256) {
        int row = idx >> 4, ck = idx & 15;
        int t = min(t0 + row, Lin - 1);
        int dst = row * 128 + ((ck ^ (row & 15)) * 8);
        if (stage0) {
            int pr = perm[t];
            const float* s = x0 + (size_t)pr * 128 + ck * 8;
            float4 a = *(const float4*)s;
            float4 bq = *(const float4*)(s + 4);
            uint4 v;
            v.x = pack2(a.x, a.y);  v.y = pack2(a.z, a.w);
            v.z = pack2(bq.x, bq.y); v.w = pack2(bq.z, bq.w);
            *(uint4*)&xin[dst] = v;
        } else {
            *(uint4*)&xin[dst] = *(const uint4*)&Xin[(size_t)t * 128 + ck * 8];
        }
    }
    __syncthreads();

    // stage A: 5 tiles -> mid
    {
        float bias_r[16];
#pragma unroll
        for (int r = 0; r < 16; ++r)
            bias_r[r] = Bst2[w * 32 + (r & 3) + 8 * (r >> 2) + 4 * h];
#pragma unroll
        for (int ti = 0; ti < 5; ++ti) {
            const int p = 32 * ti + n31;
            const int r0 = min(p, 131), r1 = min(p + 1, 131);
            const ushort* sp0 = xin + r0 * 128;
            const ushort* sp1 = xin + r1 * 128;
            const int m0 = r0 & 15, m1 = r1 & 15;
            v16f acc = ZACC;
#pragma unroll
            for (int s = 0; s < 8; ++s)
                acc = __builtin_amdgcn_mfma_f32_32x32x16_bf16(
                    af[s], *(const v8bf*)&sp0[((2 * s + h) ^ m0) * 8], acc, 0, 0, 0);
#pragma unroll
            for (int s = 0; s < 8; ++s)
                acc = __builtin_amdgcn_mfma_f32_32x32x16_bf16(
                    af[8 + s], *(const v8bf*)&sp1[((2 * s + h) ^ m1) * 8], acc, 0, 0, 0);
            const int u1 = 16 * ti + (n31 >> 1);
            const bool act = !(lane & 1) && (u1 < 65);
#pragma unroll
            for (int q = 0; q < 4; ++q) {
                float pv[4];
#pragma unroll
                for (int j = 0; j < 4; ++j) {
                    float y = leaky(acc[4 * q + j] + bias_r[4 * q + j]);
                    float y2 = __shfl_xor(y, 1, 64);
                    pv[j] = fmaxf(y, y2);
                }
                if (act) {
                    uint2 v;
                    v.x = pack2(pv[0], pv[1]);
                    v.y = pack2(pv[2], pv[3]);
                    *(uint2*)&mid[u1 * 128 + (((4 * w + q) ^ (u1 & 15)) * 8) + 4 * h] = v;
                }
            }
        }
    }
    __syncthreads();

    // stage B: 2 tiles -> global
    {
        float bias_r[16];
#pragma unroll
        for (int r = 0; r < 16; ++r)
            bias_r[r] = Bst2[128 + w * 32 + (r & 3) + 8 * (r >> 2) + 4 * h];
#pragma unroll
        for (int ti = 0; ti < 2; ++ti) {
            const int p = 32 * ti + n31;
            const ushort* sp0 = mid + p * 128;
            const ushort* sp1 = mid + (p + 1) * 128;
            const int m0 = p & 15, m1 = (p + 1) & 15;
            v16f acc = ZACC;
#pragma unroll
            for (int s = 0; s < 8; ++s)
                acc = __builtin_amdgcn_mfma_f32_32x32x16_bf16(
                    af[s], *(const v8bf*)&sp0[((2 * s + h) ^ m0) * 8], acc, 0, 0, 0);
#pragma unroll
            for (int s = 0; s < 8; ++s)
                acc = __builtin_amdgcn_mfma_f32_32x32x16_bf16(
                    af[8 + s], *(const v8bf*)&sp1[((2 * s + h) ^ m1) * 8], acc, 0, 0, 0);
            const int u2 = U + 16 * ti + (n31 >> 1);
            const bool act = !(lane & 1) && (u2 < Lp2);
#pragma unroll
            for (int q = 0; q < 4; ++q) {
                float pv[4];
#pragma unroll
                for (int j = 0; j < 4; ++j) {
                    float y = leaky(acc[4 * q + j] + bias_r[4 * q + j]);
                    float y2 = __shfl_xor(y, 1, 64);
                    pv[j] = fmaxf(y, y2);
                }
                if (act) {
                    uint2 v;
                    v.x = pack2(pv[0], pv[1]);
                    v.y = pack2(pv[2], pv[3]);
                    *(uint2*)&Y[(size_t)u2 * 128 + w * 32 + 8 * q + 4 * h] = v;
                }
            }
        }
    }
}

// ---------------------------------------------------------------------------
// Stages 10..17 (Lin=511 -> 1), single block, global ping-pong (unswizzled rows).
__device__ void do_tail(const ushort* __restrict__ Xg, ushort* __restrict__ T0,
                        ushort* __restrict__ T1, const v8bf* af,
                        const float* __restrict__ BstAll, float* __restrict__ out) {
    const int tid = threadIdx.x;
    const int lane = tid & 63;
    const int w = tid >> 6;
    const int n31 = lane & 31;
    const int h = lane >> 5;

    int Lin = 511;
    const ushort* src = Xg;
    for (int st = 0; st < 8; ++st) {
        const int Lp = (Lin - 1) >> 1;
        float bias_r[16];
#pragma unroll
        for (int r = 0; r < 16; ++r)
            bias_r[r] = BstAll[(10 + st) * 128 + w * 32 + (r & 3) + 8 * (r >> 2) + 4 * h];
        ushort* dst = (st & 1) ? T1 : T0;
        const int ntiles = (Lin - 1 + 31) >> 5;
        for (int ti = 0; ti < ntiles; ++ti) {
            const int t = ti * 32 + n31;
            const int r0 = min(t, Lin - 1), r1 = min(t + 1, Lin - 1);
            const ushort* p0 = src + (size_t)r0 * 128 + h * 8;
            const ushort* p1 = src + (size_t)r1 * 128 + h * 8;
            v16f acc = ZACC;
#pragma unroll
            for (int s = 0; s < 8; ++s)
                acc = __builtin_amdgcn_mfma_f32_32x32x16_bf16(
                    af[s], *(const v8bf*)&p0[s * 16], acc, 0, 0, 0);
#pragma unroll
            for (int s = 0; s < 8; ++s)
                acc = __builtin_amdgcn_mfma_f32_32x32x16_bf16(
                    af[8 + s], *(const v8bf*)&p1[s * 16], acc, 0, 0, 0);
            const int u = t >> 1;
            const bool act = !(lane & 1) && (u < Lp);
#pragma unroll
            for (int q = 0; q < 4; ++q) {
                float pv[4];
#pragma unroll
                for (int j = 0; j < 4; ++j) {
                    float y = leaky(acc[4 * q + j] + bias_r[4 * q + j]);
                    float y2 = __shfl_xor(y, 1, 64);
                    pv[j] = fmaxf(y, y2);
                }
                if (act) {
                    if (st < 7) {
                        uint2 v;
                        v.x = pack2(pv[0], pv[1]);
                        v.y = pack2(pv[2], pv[3]);
                        *(uint2*)&dst[u * 128 + w * 32 + 8 * q + 4 * h] = v;
                    } else {
                        float4 o = {pv[0], pv[1], pv[2], pv[3]};
                        *(float4*)&out[w * 32 + 8 * q + 4 * h] = o;
                    }
                }
            }
        }
        __threadfence();   // drain stores + invalidate L1 before re-reading
        __syncthreads();
        src = dst;
        Lin = Lp;
    }
}

// ---------------------------------------------------------------------------
// Phase 0: effective bias (18 stages) + A=[W0|W1] repack, spread over the grid.
__device__ void do_prep(int gt, const float* __restrict__ Wf, const float* __restrict__ bv,
                        const float* __restrict__ depth, float* __restrict__ Bst,
                        ushort* __restrict__ A) {
    if (gt < 2304) {
        int i = gt >> 7, o = gt & 127;
        const float* Wo = Wf + (size_t)o * 512 + 256;
        const float* di = depth + (size_t)i * 128;
        float s = bv[o];
#pragma unroll 8
        for (int c = 0; c < 128; ++c) s += di[c] * (Wo[2 * c] + Wo[2 * c + 1]);
        Bst[i * 128 + o] = s;
    }
    int gr = gt - 2304;
    if (gr >= 0 && gr < 32768) {
        int o = gr >> 8, c = gr & 255;
        float v = (c < 128) ? Wf[(size_t)o * 512 + 2 * c]
                            : Wf[(size_t)o * 512 + 2 * (c - 128) + 1];
        A[o * 256 + c] = f2bf(v);
    }
}

// ---------------------------------------------------------------------------
__global__ __launch_bounds__(256, 2)
void mono_kernel(const float* __restrict__ x0, const float* __restrict__ depth,
                 const float* __restrict__ Wf, const float* __restrict__ bv,
                 const int* __restrict__ perm, float* __restrict__ Bst,
                 ushort* __restrict__ A, ushort* __restrict__ R0,
                 ushort* __restrict__ R1, float* __restrict__ out) {
    __shared__ __align__(16) ushort xin[132 * 128];
    __shared__ __align__(16) ushort mid[65 * 128];
    cg::grid_group grid = cg::this_grid();
    const int bid = blockIdx.x, nb = gridDim.x;

    do_prep(bid * 256 + threadIdx.x, Wf, bv, depth, Bst, A);
    grid.sync();

    v8bf af[16];
    load_af(A, af);

    for (int g = bid; g < 4096; g += nb)
        do_pair(g * 32, nullptr, x0, perm, af, Bst, R0, 524288, 131071, 1, xin, mid);
    grid.sync();
    for (int g = bid; g < 1024; g += nb)
        do_pair(g * 32, R0, nullptr, nullptr, af, Bst + 2 * 128, R1, 131071, 32767, 0, xin, mid);
    grid.sync();
    for (int g = bid; g < 256; g += nb)
        do_pair(g * 32, R1, nullptr, nullptr, af, Bst + 4 * 128, R0, 32767, 8191, 0, xin, mid);
    grid.sync();
    for (int g = bid; g < 64; g += nb)
        do_pair(g * 32, R0, nullptr, nullptr, af, Bst + 6 * 128, R1, 8191, 2047, 0, xin, mid);
    grid.sync();
    for (int g = bid; g < 16; g += nb)
        do_pair(g * 32, R1, nullptr, nullptr, af, Bst + 8 * 128, R0, 2047, 511, 0, xin, mid);
    grid.sync();

    if (bid == 0) do_tail(R0, R1, R1 + 255 * 128, af, Bst, out);
}

// ---------------------------------------------------------------------------
// Fallback path (non-cooperative), reuses the same device functions.
__global__ void prep_kernel(const float* __restrict__ Wf, const float* __restrict__ bv,
                            const float* __restrict__ depth, float* __restrict__ Bst,
                            ushort* __restrict__ A) {
    do_prep(blockIdx.x * 256 + threadIdx.x, Wf, bv, depth, Bst, A);
}

__global__ __launch_bounds__(256)
void pair_kernel(const ushort* __restrict__ Xin, const float* __restrict__ x0,
                 const int* __restrict__ perm, const ushort* __restrict__ A,
                 const float* __restrict__ Bst2, ushort* __restrict__ Y,
                 int Lin, int Lp2, int stage0) {
    __shared__ __align__(16) ushort xin[132 * 128];
    __shared__ __align__(16) ushort mid[65 * 128];
    v8bf af[16];
    load_af(A, af);
    do_pair(blockIdx.x * 32, Xin, x0, perm, af, Bst2, Y, Lin, Lp2, stage0, xin, mid);
}

__global__ __launch_bounds__(256)
void tail_kernel(const ushort* __restrict__ Xg, ushort* __restrict__ T0,
                 ushort* __restrict__ T1, const ushort* __restrict__ A,
                 const float* __restrict__ BstAll, float* __restrict__ out) {
    v8bf af[16];
    load_af(A, af);
    do_tail(Xg, T0, T1, af, BstAll, out);
}

// ---------------------------------------------------------------------------
extern "C" void kernel_launch(void* const* d_in, const int* in_sizes, int n_in,
                              void* d_out, int out_size, void* d_ws, size_t ws_size,
                              hipStream_t stream) {
    const float* x     = (const float*)d_in[0];   // [524288][128]
    const float* depth = (const float*)d_in[1];   // [32][128]
    const float* W     = (const float*)d_in[2];   // [128][256][2]
    const float* b     = (const float*)d_in[3];   // [128]
    const int*   perm  = (const int*)d_in[4];     // [524288]
    float* out = (float*)d_out;                   // [1][128] fp32

    char* ws = (char*)d_ws;
    float*  Bst = (float*)ws;                                            // 18*128 fp32
    ushort* A   = (ushort*)(ws + 16384);                                 // 128*256 bf16
    ushort* R0  = (ushort*)(ws + 16384 + 65536);                         // 131071 rows max
    ushort* R1  = (ushort*)(ws + 16384 + 65536 + (size_t)131071 * 256);  // 32767 rows max

    int maxb = 0;
    hipError_t qe = hipOccupancyMaxActiveBlocksPerMultiprocessor(&maxb, mono_kernel, 256, 0);
    if (qe != hipSuccess || maxb < 1) maxb = 0;
    int nblk = maxb * 256;            // 256 CUs
    if (nblk > 1024) nblk = 1024;

    hipError_t rc = hipErrorUnknown;
    if (nblk >= 256) {
        const float* xa = x; const float* da = depth; const float* Wa = W;
        const float* ba = b; const int* pa = perm;
        float* Ba = Bst; ushort* Aa = A; ushort* R0a = R0; ushort* R1a = R1;
        float* oa = out;
        void* args[] = {&xa, &da, &Wa, &ba, &pa, &Ba, &Aa, &R0a, &R1a, &oa};
        rc = hipLaunchCooperativeKernel(mono_kernel, dim3(nblk), dim3(256), args, 0, stream);
    }
    if (rc != hipSuccess) {
        // fallback: 8 plain dispatches (R4-equivalent)
        prep_kernel<<<137, 256, 0, stream>>>(W, b, depth, Bst, A);
        pair_kernel<<<4096, 256, 0, stream>>>(nullptr, x, perm, A, Bst, R0,
                                              524288, 131071, 1);
        pair_kernel<<<1024, 256, 0, stream>>>(R0, nullptr, nullptr, A, Bst + 2 * 128, R1,
                                              131071, 32767, 0);
        pair_kernel<<<256, 256, 0, stream>>>(R1, nullptr, nullptr, A, Bst + 4 * 128, R0,
                                             32767, 8191, 0);
        pair_kernel<<<64, 256, 0, stream>>>(R0, nullptr, nullptr, A, Bst + 6 * 128, R1,
                                            8191, 2047, 0);
        pair_kernel<<<16, 256, 0, stream>>>(R1, nullptr, nullptr, A, Bst + 8 * 128, R0,
                                            2047, 511, 0);
        tail_kernel<<<1, 256, 0, stream>>>(R0, R1, R1 + 255 * 128, A, Bst, out);
    }
}